// Round 3
// baseline (303.582 us; speedup 1.0000x reference)
//
#include <hip/hip_runtime.h>
#include <hip/hip_fp16.h>
#include <cstdint>

typedef unsigned short ushort_t;
typedef _Float16 f16x8 __attribute__((ext_vector_type(8)));  // 8 f16 (4 VGPRs) for MFMA
typedef float f32x4 __attribute__((ext_vector_type(4)));
typedef unsigned int u32x4 __attribute__((ext_vector_type(4)));

#define M_TOT  32768
#define K_EMB  256
#define K_CORE 512
#define ACT    12

__device__ __forceinline__ unsigned int pack2h(float a, float b) {
    __half2 h = __floats2half2_rn(a, b);
    union { __half2 h2; unsigned int u; } v; v.h2 = h; return v.u;
}

// ---------- kernel 1 (merged prep): blocks 0..63 transpose W1[0:256,:] -> f16 W1T[1024][256];
// blocks 64..319: cp[b][n] = b1[n] + sum_k core[b][k]*W1[256+k][n], K-split x4 + LDS reduce.
__global__ __launch_bounds__(1024) void prep_k(const float* __restrict__ W1,
                                               ushort_t* __restrict__ W1T,
                                               const float* __restrict__ core,
                                               const float* __restrict__ b1,
                                               float* __restrict__ cp) {
    __shared__ float tile[64][65];
    __shared__ float part[3][256];
    const int id = blockIdx.x;
    const int t = threadIdx.x;
    if (id < 64) {
        // ---- transpose+convert one 64x64 tile (1024 threads: 1 float4 load, 1 uint2 store) ----
        const int k0 = (id & 3) * 64, n0 = (id >> 2) * 64;
        const int r = t >> 4, c4 = (t & 15) * 4;
        const float4 v = *(const float4*)(W1 + (size_t)(k0 + r) * 1024 + n0 + c4);
        tile[r][c4 + 0] = v.x; tile[r][c4 + 1] = v.y;
        tile[r][c4 + 2] = v.z; tile[r][c4 + 3] = v.w;
        __syncthreads();
        uint2 o;
        o.x = pack2h(tile[c4 + 0][r], tile[c4 + 1][r]);
        o.y = pack2h(tile[c4 + 2][r], tile[c4 + 3][r]);
        *(uint2*)(W1T + (size_t)(n0 + r) * 256 + k0 + c4) = o;
    } else {
        // ---- corepart: 4-way K-split, 16 waves/block for latency hiding ----
        const int xb = id - 64;
        const int b = xb >> 2;                 // 0..63
        const int nl = t & 255;
        const int n = (xb & 3) * 256 + nl;     // 0..1023
        const int kq = t >> 8;                 // 0..3, each owns 128 k
        const float* cr = core + (size_t)b * K_CORE + kq * 128;
        const float* wp = W1 + (size_t)(K_EMB + kq * 128) * 1024 + n;
        float s0 = 0.f, s1 = 0.f, s2 = 0.f, s3 = 0.f;
#pragma unroll 8
        for (int k = 0; k < 128; k += 4) {
            s0 += cr[k + 0] * wp[(size_t)(k + 0) * 1024];
            s1 += cr[k + 1] * wp[(size_t)(k + 1) * 1024];
            s2 += cr[k + 2] * wp[(size_t)(k + 2) * 1024];
            s3 += cr[k + 3] * wp[(size_t)(k + 3) * 1024];
        }
        const float s = (s0 + s1) + (s2 + s3);
        if (kq) part[kq - 1][nl] = s;
        __syncthreads();
        if (kq == 0)
            cp[b * 1024 + n] = b1[n] + s + part[0][nl] + part[1][nl] + part[2][nl];
    }
}

// ---------- kernel 2 (fused): BM=64 rows/block, 512 blocks, 3 blocks/CU (35 KB LDS).
// A-tile (64x256 f16, XOR-swizzled) resident in LDS, staged ONCE -> single barrier.
// B fragments loaded DIRECTLY global->VGPR from L2-resident w1t (512 KB): the K-loop
// has NO barriers, NO ds_writes, NO vmcnt(0) drains -- pure load+MFMA straight-line
// code, pipelined by the compiler and overlapped across 12 waves/CU.
// MFMA operands swapped: D col=lane16=m, row=qd*4+r=n -> float4 out1 stores.
__global__ __launch_bounds__(256, 3) void fused_k(const float* __restrict__ emb,
                                                  const ushort_t* __restrict__ w1t,
                                                  const float* __restrict__ cp,
                                                  const float* __restrict__ W2,
                                                  const float* __restrict__ b2,
                                                  const int* __restrict__ nr_units,
                                                  const int* __restrict__ nr_flags,
                                                  float* __restrict__ out0,
                                                  float* __restrict__ out1) {
    __shared__ __align__(16) ushort_t Asl[64 * 256];       // 32 KB, row stride 512B, swizzle g^=(r&7)
    __shared__ __align__(16) float logitAcc[64][ACT];      // 3 KB

    const int t = threadIdx.x;
    const int w = t >> 6, L = t & 63;
    const int lane16 = L & 15, qd = L >> 4;
    const int m0 = blockIdx.x * 64;
    const int bb = blockIdx.x >> 3;

    // ---- zero logit accumulator (ordered by the staging barrier) ----
    if (t < 192) ((f32x4*)logitAcc)[t] = (f32x4){0.f, 0.f, 0.f, 0.f};

    // ---- stage FULL A tile: 64 rows x 256 k, f32 -> f16, XOR-swizzled (once per block) ----
    {
        const int g = t & 31;          // 8-f16 group within row (0..31)
        const int rsub = t >> 5;       // 0..7
#pragma unroll
        for (int p = 0; p < 8; ++p) {
            const int r = p * 8 + rsub;
            const float* src = emb + (size_t)(m0 + r) * K_EMB + g * 8;
            const f32x4 v0 = __builtin_nontemporal_load((const f32x4*)src);
            const f32x4 v1 = __builtin_nontemporal_load((const f32x4*)src + 1);
            u32x4 pk;
            pk[0] = pack2h(v0[0], v0[1]); pk[1] = pack2h(v0[2], v0[3]);
            pk[2] = pack2h(v1[0], v1[1]); pk[3] = pack2h(v1[2], v1[3]);
            *(u32x4*)((char*)Asl + r * 512 + ((g ^ (r & 7)) << 4)) = pk;
        }
    }
    __syncthreads();   // A tile + logitAcc-zero visible; LAST barrier before the reduce

    // ---- A-fragment read bases (swizzled), B-fragment global base ----
    const int araw = lane16 * 512;                 // + mi*8192 + per-ks XOR'd group
    const int axor = lane16 & 7;
    // B-frag: lane reads w1t[n_row][ks*32 + qd*8 .. +8), n_row = nt*128 + w*32 + ni*16 + lane16
    const ushort_t* gB = w1t + (size_t)(w * 32 + lane16) * 256 + qd * 8;

    // ---- accumulators ----
    f32x4 la[4][3];                        // logit partials: per lane, 4 m-rows x 12 acts
#pragma unroll
    for (int mi = 0; mi < 4; ++mi)
#pragma unroll
        for (int c = 0; c < 3; ++c) la[mi][c] = (f32x4){0.f, 0.f, 0.f, 0.f};

    for (int nt = 0; nt < 8; ++nt) {
        f32x4 acc[2][4];                   // [ni][mi]: D rows=n (qd*4+r), cols=m (lane16)
#pragma unroll
        for (int ni = 0; ni < 2; ++ni)
#pragma unroll
            for (int mi = 0; mi < 4; ++mi) acc[ni][mi] = (f32x4){0.f, 0.f, 0.f, 0.f};

        const ushort_t* gBt = gB + (size_t)nt * 128 * 256;
#pragma unroll
        for (int ks = 0; ks < 8; ++ks) {
            const f16x8 bf0 = *(const f16x8*)(gBt + ks * 32);
            const f16x8 bf1 = *(const f16x8*)(gBt + ks * 32 + 16 * 256);
            const int ga = (((ks << 2) | qd) ^ axor) << 4;
            f16x8 af[4];
#pragma unroll
            for (int mi = 0; mi < 4; ++mi)
                af[mi] = *(const f16x8*)((const char*)Asl + mi * 8192 + araw + ga);
#pragma unroll
            for (int mi = 0; mi < 4; ++mi)
                acc[0][mi] = __builtin_amdgcn_mfma_f32_16x16x32_f16(bf0, af[mi], acc[0][mi], 0, 0, 0);
#pragma unroll
            for (int mi = 0; mi < 4; ++mi)
                acc[1][mi] = __builtin_amdgcn_mfma_f32_16x16x32_f16(bf1, af[mi], acc[1][mi], 0, 0, 0);
        }

        // ---- per-n-tile epilogue: +cp, relu, float4 store h, logit partials ----
#pragma unroll
        for (int ni = 0; ni < 2; ++ni) {
            const int nbase = nt * 128 + w * 32 + ni * 16 + qd * 4;
            const f32x4 cpv = *(const f32x4*)(cp + bb * 1024 + nbase);
#pragma unroll
            for (int mi = 0; mi < 4; ++mi) {
                f32x4 v = acc[ni][mi] + cpv;
#pragma unroll
                for (int j = 0; j < 4; ++j) v[j] = v[j] > 0.f ? v[j] : 0.f;
                acc[ni][mi] = v;
                const size_t m = (size_t)(m0 + mi * 16 + lane16);
                __builtin_nontemporal_store(v, (f32x4*)(out1 + m * 1024 + nbase));
            }
#pragma unroll
            for (int r = 0; r < 4; ++r) {
                const f32x4* wp = (const f32x4*)(W2 + (size_t)(nbase + r) * ACT);
                const f32x4 w2a = wp[0], w2b = wp[1], w2c = wp[2];
#pragma unroll
                for (int mi = 0; mi < 4; ++mi) {
                    const float vv = acc[ni][mi][r];
                    la[mi][0] += w2a * vv;
                    la[mi][1] += w2b * vv;
                    la[mi][2] += w2c * vv;
                }
            }
        }
    }

    // ---- reduce logit partials across qd (lanes l, l^16, l^32, l^48 share lane16) ----
#pragma unroll
    for (int mi = 0; mi < 4; ++mi)
#pragma unroll
        for (int c = 0; c < 3; ++c)
#pragma unroll
            for (int j = 0; j < 4; ++j) {
                la[mi][c][j] += __shfl_xor(la[mi][c][j], 16, 64);
                la[mi][c][j] += __shfl_xor(la[mi][c][j], 32, 64);
            }
    // cross-wave combine via LDS float atomics (4-way contention max)
    if (L < 16) {
#pragma unroll
        for (int mi = 0; mi < 4; ++mi) {
            const int row = mi * 16 + L;
#pragma unroll
            for (int c = 0; c < 3; ++c)
#pragma unroll
                for (int j = 0; j < 4; ++j)
                    atomicAdd(&logitAcc[row][c * 4 + j], la[mi][c][j]);
        }
    }
    __syncthreads();

    // ---- softmax + range mask, one thread per row ----
    if (t < 64) {
        float lg[ACT];
#pragma unroll
        for (int a = 0; a < ACT; ++a) lg[a] = logitAcc[t][a] + b2[a];
        float mx = lg[0];
#pragma unroll
        for (int a = 1; a < ACT; ++a) mx = fmaxf(mx, lg[a]);
        float s = 0.f;
#pragma unroll
        for (int a = 0; a < ACT; ++a) { lg[a] = __expf(lg[a] - mx); s += lg[a]; }
        const float inv = 1.f / s;
        const int m = m0 + t;
        const int u = m & 511;
        const float msk = (u >= nr_flags[bb] && u < nr_units[bb]) ? 1.0f : 1e-9f;
        f32x4 o0, o1, o2;
#pragma unroll
        for (int j = 0; j < 4; ++j) {
            o0[j] = lg[j] * inv * msk;
            o1[j] = lg[j + 4] * inv * msk;
            o2[j] = lg[j + 8] * inv * msk;
        }
        f32x4* op = (f32x4*)(out0 + (size_t)m * ACT);
        __builtin_nontemporal_store(o0, op + 0);
        __builtin_nontemporal_store(o1, op + 1);
        __builtin_nontemporal_store(o2, op + 2);
    }
}

extern "C" void kernel_launch(void* const* d_in, const int* in_sizes, int n_in,
                              void* d_out, int out_size, void* d_ws, size_t ws_size,
                              hipStream_t stream) {
    const float* core   = (const float*)d_in[0];
    const float* emb    = (const float*)d_in[1];
    const int* nr_units = (const int*)d_in[2];
    const int* nr_flags = (const int*)d_in[3];
    const float* W1     = (const float*)d_in[4];
    const float* b1     = (const float*)d_in[5];
    const float* W2     = (const float*)d_in[6];
    const float* b2     = (const float*)d_in[7];

    float* out0 = (float*)d_out;                       // probs [32768*12] f32
    float* out1 = out0 + (size_t)M_TOT * ACT;          // embedding [32768*1024] f32

    ushort_t* w1t = (ushort_t*)d_ws;                   // f16 [1024][256] = 512 KB
    float* cp = (float*)((char*)d_ws + (size_t)1024 * 256 * 2); // [64][1024] f32

    prep_k<<<dim3(320), 1024, 0, stream>>>(W1, w1t, core, b1, cp);
    fused_k<<<dim3(512), 256, 0, stream>>>(emb, w1t, cp, W2, b2, nr_units, nr_flags, out0, out1);
}

// Round 4
// 228.899 us; speedup vs baseline: 1.3263x; 1.3263x over previous
//
#include <hip/hip_runtime.h>
#include <hip/hip_fp16.h>
#include <cstdint>

typedef unsigned short ushort_t;
typedef _Float16 f16x8 __attribute__((ext_vector_type(8)));  // 8 f16 (4 VGPRs) for MFMA
typedef float f32x4 __attribute__((ext_vector_type(4)));
typedef unsigned int u32x4 __attribute__((ext_vector_type(4)));

#define M_TOT  32768
#define K_EMB  256
#define K_CORE 512
#define ACT    12

__device__ __forceinline__ unsigned int pack2h(float a, float b) {
    __half2 h = __floats2half2_rn(a, b);
    union { __half2 h2; unsigned int u; } v; v.h2 = h; return v.u;
}

// async global->LDS, 16 B per lane (global_load_lds_dwordx4). LDS dest must be
// wave-uniform base + lane*16 (linear); source is per-lane.
__device__ __forceinline__ void glds16(const ushort_t* g, ushort_t* l) {
    __builtin_amdgcn_global_load_lds((const __attribute__((address_space(1))) void*)g,
                                     (__attribute__((address_space(3))) void*)l, 16, 0, 0);
}

// ---------- kernel 1 (merged prep): blocks 0..63 transpose W1[0:256,:] into the
// PRE-SWIZZLED slab layout w1t_s[it=nt*8+ks][r][gs][8]: element (n = nt*128+r,
// k = ks*32+g*8+e) stored at slab it, offset r*32 + (g ^ ((r>>1)&3))*8 + e (ushorts).
// Linear glds staging of a slab then reproduces round-2's conflict-free LDS image.
// blocks 64..319: cp[b][n] = b1[n] + sum_k core[b][k]*W1[256+k][n], K-split x4.
__global__ __launch_bounds__(1024) void prep_k(const float* __restrict__ W1,
                                               ushort_t* __restrict__ W1T,
                                               const float* __restrict__ core,
                                               const float* __restrict__ b1,
                                               float* __restrict__ cp) {
    __shared__ float tile[64][65];
    __shared__ float part[3][256];
    const int id = blockIdx.x;
    const int t = threadIdx.x;
    if (id < 64) {
        // ---- transpose+convert one 64x64 tile (1024 threads: 1 float4 load, 1 uint2 store) ----
        const int k0 = (id & 3) * 64, n0 = (id >> 2) * 64;
        const int r = t >> 4, c4 = (t & 15) * 4;
        const float4 v = *(const float4*)(W1 + (size_t)(k0 + r) * 1024 + n0 + c4);
        tile[r][c4 + 0] = v.x; tile[r][c4 + 1] = v.y;
        tile[r][c4 + 2] = v.z; tile[r][c4 + 3] = v.w;
        __syncthreads();
        uint2 o;
        o.x = pack2h(tile[c4 + 0][r], tile[c4 + 1][r]);
        o.y = pack2h(tile[c4 + 2][r], tile[c4 + 3][r]);
        const int n  = n0 + r;          // 0..1023
        const int kk = k0 + c4;         // 0..255, multiple of 4
        const int nt = n >> 7, rr = n & 127;
        const int ks = kk >> 5, k32 = kk & 31;
        const int g  = k32 >> 3, gs = g ^ ((rr >> 1) & 3);
        const size_t addr = ((size_t)(nt * 8 + ks) * 128 + rr) * 32 + gs * 8 + (k32 & 7);
        *(uint2*)(W1T + addr) = o;
    } else {
        // ---- corepart: 4-way K-split, 16 waves/block for latency hiding ----
        const int xb = id - 64;
        const int b = xb >> 2;                 // 0..63
        const int nl = t & 255;
        const int n = (xb & 3) * 256 + nl;     // 0..1023
        const int kq = t >> 8;                 // 0..3, each owns 128 k
        const float* cr = core + (size_t)b * K_CORE + kq * 128;
        const float* wp = W1 + (size_t)(K_EMB + kq * 128) * 1024 + n;
        float s0 = 0.f, s1 = 0.f, s2 = 0.f, s3 = 0.f;
#pragma unroll 8
        for (int k = 0; k < 128; k += 4) {
            s0 += cr[k + 0] * wp[(size_t)(k + 0) * 1024];
            s1 += cr[k + 1] * wp[(size_t)(k + 1) * 1024];
            s2 += cr[k + 2] * wp[(size_t)(k + 2) * 1024];
            s3 += cr[k + 3] * wp[(size_t)(k + 3) * 1024];
        }
        const float s = (s0 + s1) + (s2 + s3);
        if (kq) part[kq - 1][nl] = s;
        __syncthreads();
        if (kq == 0)
            cp[b * 1024 + n] = b1[n] + s + part[0][nl] + part[1][nl] + part[2][nl];
    }
}

// ---------- kernel 2 (fused): BM=64, 512 blocks, 2 blocks/CU (59 KB LDS).
// A-tile resident in LDS (staged once, one barrier). B: per-wave PRIVATE 2 KB slabs
// (wave w only reads rows [w*32,w*32+32)) staged via global_load_lds into a
// triple-buffer, depth-2 prefetch, counted s_waitcnt vmcnt(2) -- the K-loop has
// ZERO barriers and ZERO reg-roundtrip staging; every wave is an independent
// pipeline. w1t is pre-swizzled so linear glds yields conflict-free ds_read_b128.
__global__ __launch_bounds__(256, 2) void fused_k(const float* __restrict__ emb,
                                                  const ushort_t* __restrict__ w1t,
                                                  const float* __restrict__ cp,
                                                  const float* __restrict__ W2,
                                                  const float* __restrict__ b2,
                                                  const int* __restrict__ nr_units,
                                                  const int* __restrict__ nr_flags,
                                                  float* __restrict__ out0,
                                                  float* __restrict__ out1) {
    __shared__ __align__(16) ushort_t Asl[64 * 256];       // 32 KB, row stride 512B, swizzle g^=(r&7)
    __shared__ __align__(16) ushort_t Bsl[3][128 * 32];    // 3 x 8 KB slabs (per-wave private 2 KB each)
    __shared__ __align__(16) float logitAcc[64][ACT];      // 3 KB

    const int t = threadIdx.x;
    const int w = t >> 6, L = t & 63;
    const int lane16 = L & 15, qd = L >> 4;
    const int m0 = blockIdx.x * 64;
    const int bb = blockIdx.x >> 3;

    // ---- zero logit accumulator (ordered by the staging barrier) ----
    if (t < 192) ((f32x4*)logitAcc)[t] = (f32x4){0.f, 0.f, 0.f, 0.f};

    // ---- stage FULL A tile: 64 rows x 256 k, f32 -> f16, XOR-swizzled (once per block) ----
    {
        const int g = t & 31;          // 8-f16 group within row (0..31)
        const int rsub = t >> 5;       // 0..7
#pragma unroll
        for (int p = 0; p < 8; ++p) {
            const int r = p * 8 + rsub;
            const float* src = emb + (size_t)(m0 + r) * K_EMB + g * 8;
            const f32x4 v0 = __builtin_nontemporal_load((const f32x4*)src);
            const f32x4 v1 = __builtin_nontemporal_load((const f32x4*)src + 1);
            u32x4 pk;
            pk[0] = pack2h(v0[0], v0[1]); pk[1] = pack2h(v0[2], v0[3]);
            pk[2] = pack2h(v1[0], v1[1]); pk[3] = pack2h(v1[2], v1[3]);
            *(u32x4*)((char*)Asl + r * 512 + ((g ^ (r & 7)) << 4)) = pk;
        }
    }

    // ---- prologue: issue B slabs for it=0,1 (wave-private regions) ----
    {
        const ushort_t* s0 = w1t + (size_t)0 * 4096 + w * 1024 + L * 8;
        glds16(s0,        &Bsl[0][w * 1024]);
        glds16(s0 + 512,  &Bsl[0][w * 1024 + 512]);
        const ushort_t* s1 = w1t + (size_t)1 * 4096 + w * 1024 + L * 8;
        glds16(s1,        &Bsl[1][w * 1024]);
        glds16(s1 + 512,  &Bsl[1][w * 1024 + 512]);
    }
    __syncthreads();   // A tile + logitAcc-zero visible (also drains prologue glds)

    // ---- fragment read bases ----
    const int araw = lane16 * 512;                 // + mi*8192 + per-ks XOR'd group
    const int axor = lane16 & 7;
    const int bswz = (qd ^ ((lane16 >> 1) & 3)) << 4;
    const int boffc0 = (w * 32 + 0 * 16 + lane16) * 64 + bswz;
    const int boffc1 = (w * 32 + 1 * 16 + lane16) * 64 + bswz;
    const ushort_t* gwav = w1t + w * 1024 + L * 8;  // + it*4096 per slab

    // ---- accumulators ----
    f32x4 la[4][3];                        // logit partials: per lane, 4 m-rows x 12 acts
#pragma unroll
    for (int mi = 0; mi < 4; ++mi)
#pragma unroll
        for (int c = 0; c < 3; ++c) la[mi][c] = (f32x4){0.f, 0.f, 0.f, 0.f};

    int cur = 0, nb = 2;                   // rotating buffer indices: it%3, (it+2)%3
    for (int nt = 0; nt < 8; ++nt) {
        f32x4 acc[2][4];                   // [ni][mi]: D rows=n (qd*4+r), cols=m (lane16)
#pragma unroll
        for (int ni = 0; ni < 2; ++ni)
#pragma unroll
            for (int mi = 0; mi < 4; ++mi) acc[ni][mi] = (f32x4){0.f, 0.f, 0.f, 0.f};

#pragma unroll
        for (int ks = 0; ks < 8; ++ks) {
            const int it = nt * 8 + ks;
            // counted wait: the 2 glds for buf[cur] were issued 2 iterations ago;
            // at most 2 newer glds are outstanding. Never drains the pipeline.
            asm volatile("s_waitcnt vmcnt(2)" ::: "memory");

            const char* bbase = (const char*)&Bsl[cur][0];
            const f16x8 bf0 = *(const f16x8*)(bbase + boffc0);
            const f16x8 bf1 = *(const f16x8*)(bbase + boffc1);
            const int ga = (((ks << 2) | qd) ^ axor) << 4;
            f16x8 af[4];
#pragma unroll
            for (int mi = 0; mi < 4; ++mi)
                af[mi] = *(const f16x8*)((const char*)Asl + mi * 8192 + araw + ga);

            if (it < 62) {                 // issue depth-2 prefetch into buf[(it+2)%3]
                const ushort_t* s = gwav + (size_t)(it + 2) * 4096;
                ushort_t* d = &Bsl[nb][w * 1024];
                glds16(s,       d);
                glds16(s + 512, d + 512);
            }

#pragma unroll
            for (int mi = 0; mi < 4; ++mi)
                acc[0][mi] = __builtin_amdgcn_mfma_f32_16x16x32_f16(bf0, af[mi], acc[0][mi], 0, 0, 0);
#pragma unroll
            for (int mi = 0; mi < 4; ++mi)
                acc[1][mi] = __builtin_amdgcn_mfma_f32_16x16x32_f16(bf1, af[mi], acc[1][mi], 0, 0, 0);

            cur = (cur == 2) ? 0 : cur + 1;
            nb  = (nb  == 2) ? 0 : nb  + 1;
        }

        // ---- per-n-tile epilogue: +cp, relu, float4 store h, logit partials ----
#pragma unroll
        for (int ni = 0; ni < 2; ++ni) {
            const int nbase = nt * 128 + w * 32 + ni * 16 + qd * 4;
            const f32x4 cpv = *(const f32x4*)(cp + bb * 1024 + nbase);
#pragma unroll
            for (int mi = 0; mi < 4; ++mi) {
                f32x4 v = acc[ni][mi] + cpv;
#pragma unroll
                for (int j = 0; j < 4; ++j) v[j] = v[j] > 0.f ? v[j] : 0.f;
                acc[ni][mi] = v;
                const size_t m = (size_t)(m0 + mi * 16 + lane16);
                __builtin_nontemporal_store(v, (f32x4*)(out1 + m * 1024 + nbase));
            }
#pragma unroll
            for (int r = 0; r < 4; ++r) {
                const f32x4* wp = (const f32x4*)(W2 + (size_t)(nbase + r) * ACT);
                const f32x4 w2a = wp[0], w2b = wp[1], w2c = wp[2];
#pragma unroll
                for (int mi = 0; mi < 4; ++mi) {
                    const float vv = acc[ni][mi][r];
                    la[mi][0] += w2a * vv;
                    la[mi][1] += w2b * vv;
                    la[mi][2] += w2c * vv;
                }
            }
        }
    }

    // ---- reduce logit partials across qd (lanes l, l^16, l^32, l^48 share lane16) ----
#pragma unroll
    for (int mi = 0; mi < 4; ++mi)
#pragma unroll
        for (int c = 0; c < 3; ++c)
#pragma unroll
            for (int j = 0; j < 4; ++j) {
                la[mi][c][j] += __shfl_xor(la[mi][c][j], 16, 64);
                la[mi][c][j] += __shfl_xor(la[mi][c][j], 32, 64);
            }
    // cross-wave combine via LDS float atomics (4-way contention max)
    if (L < 16) {
#pragma unroll
        for (int mi = 0; mi < 4; ++mi) {
            const int row = mi * 16 + L;
#pragma unroll
            for (int c = 0; c < 3; ++c)
#pragma unroll
                for (int j = 0; j < 4; ++j)
                    atomicAdd(&logitAcc[row][c * 4 + j], la[mi][c][j]);
        }
    }
    __syncthreads();

    // ---- softmax + range mask, one thread per row ----
    if (t < 64) {
        float lg[ACT];
#pragma unroll
        for (int a = 0; a < ACT; ++a) lg[a] = logitAcc[t][a] + b2[a];
        float mx = lg[0];
#pragma unroll
        for (int a = 1; a < ACT; ++a) mx = fmaxf(mx, lg[a]);
        float s = 0.f;
#pragma unroll
        for (int a = 0; a < ACT; ++a) { lg[a] = __expf(lg[a] - mx); s += lg[a]; }
        const float inv = 1.f / s;
        const int m = m0 + t;
        const int u = m & 511;
        const float msk = (u >= nr_flags[bb] && u < nr_units[bb]) ? 1.0f : 1e-9f;
        f32x4 o0, o1, o2;
#pragma unroll
        for (int j = 0; j < 4; ++j) {
            o0[j] = lg[j] * inv * msk;
            o1[j] = lg[j + 4] * inv * msk;
            o2[j] = lg[j + 8] * inv * msk;
        }
        f32x4* op = (f32x4*)(out0 + (size_t)m * ACT);
        __builtin_nontemporal_store(o0, op + 0);
        __builtin_nontemporal_store(o1, op + 1);
        __builtin_nontemporal_store(o2, op + 2);
    }
}

extern "C" void kernel_launch(void* const* d_in, const int* in_sizes, int n_in,
                              void* d_out, int out_size, void* d_ws, size_t ws_size,
                              hipStream_t stream) {
    const float* core   = (const float*)d_in[0];
    const float* emb    = (const float*)d_in[1];
    const int* nr_units = (const int*)d_in[2];
    const int* nr_flags = (const int*)d_in[3];
    const float* W1     = (const float*)d_in[4];
    const float* b1     = (const float*)d_in[5];
    const float* W2     = (const float*)d_in[6];
    const float* b2     = (const float*)d_in[7];

    float* out0 = (float*)d_out;                       // probs [32768*12] f32
    float* out1 = out0 + (size_t)M_TOT * ACT;          // embedding [32768*1024] f32

    ushort_t* w1t = (ushort_t*)d_ws;                   // f16, pre-swizzled slabs, 512 KB
    float* cp = (float*)((char*)d_ws + (size_t)1024 * 256 * 2); // [64][1024] f32

    prep_k<<<dim3(320), 1024, 0, stream>>>(W1, w1t, core, b1, cp);
    fused_k<<<dim3(512), 256, 0, stream>>>(emb, w1t, cp, W2, b2, nr_units, nr_flags, out0, out1);
}